// Round 1
// baseline (706.916 us; speedup 1.0000x reference)
//
#include <hip/hip_runtime.h>

// Segment mean: x [N=1048576, D=128] fp32, B=16 contiguous segments given by
// lengths[16]. out [16,128] fp32 = per-segment column means.
//
// Phase 1: grid (XB, 16); block(s, bx) reduces rows of segment s with
//   stride XB*8, 8 rows per iteration (256 thr = 8 row-slots x 32 float4 cols).
//   Writes one [128]-float partial per block into d_ws (no atomics).
// Phase 2: grid(16) x block(128): sum XB partials per (s, d), divide by len.

#define SEG_D 128
#define NSEG 16

__global__ __launch_bounds__(256) void seg_partial_kernel(
    const float* __restrict__ x,
    const int* __restrict__ lengths,
    float* __restrict__ partial) {
  const int s  = blockIdx.y;
  const int bx = blockIdx.x;
  const int xb = gridDim.x;

  // Segment start offset and length from lengths[] (16 cached reads).
  long start = 0;
  int len = 0;
  for (int i = 0; i < NSEG; ++i) {
    int l = lengths[i];
    if (i < s) start += l;
    if (i == s) len = l;
  }

  const int ro  = threadIdx.x >> 5;         // row slot 0..7
  const int col = (threadIdx.x & 31) << 2;  // float4 column group

  float4 acc = make_float4(0.f, 0.f, 0.f, 0.f);

  int r = bx * 8 + ro;
  const float* p = x + (start + r) * (long)SEG_D + col;
  const long step_elems = (long)xb * 8 * SEG_D;
  const int step_rows = xb * 8;

  for (; r < len; r += step_rows) {
    const float4 v = *(const float4*)p;
    acc.x += v.x; acc.y += v.y; acc.z += v.z; acc.w += v.w;
    p += step_elems;
  }

  // 8-way reduction across row slots via LDS.
  __shared__ float4 red[256];
  red[threadIdx.x] = acc;
  __syncthreads();
  if (threadIdx.x < 32) {
    float4 sum = red[threadIdx.x];
#pragma unroll
    for (int i = 1; i < 8; ++i) {
      const float4 v = red[threadIdx.x + i * 32];
      sum.x += v.x; sum.y += v.y; sum.z += v.z; sum.w += v.w;
    }
    // partial[(s*XB + bx)*D + col .. +3]
    *(float4*)(partial + ((long)(s * xb + bx)) * SEG_D + col) = sum;
  }
}

__global__ __launch_bounds__(SEG_D) void seg_finish_kernel(
    const float* __restrict__ partial,
    const int* __restrict__ lengths,
    float* __restrict__ out,
    int xb) {
  const int s = blockIdx.x;
  const int d = threadIdx.x;
  float sum = 0.f;
  const float* p = partial + (long)s * xb * SEG_D + d;
  for (int b = 0; b < xb; ++b) {
    sum += p[(long)b * SEG_D];
  }
  out[s * SEG_D + d] = sum / (float)lengths[s];
}

extern "C" void kernel_launch(void* const* d_in, const int* in_sizes, int n_in,
                              void* d_out, int out_size, void* d_ws, size_t ws_size,
                              hipStream_t stream) {
  const float* x       = (const float*)d_in[0];
  // d_in[1] = segment_ids (int32) — unused; segments are contiguous, lengths suffice.
  const int*   lengths = (const int*)d_in[2];
  float*       out     = (float*)d_out;
  float*       partial = (float*)d_ws;

  // XB partial blocks per segment; cap by workspace (needs NSEG*XB*D*4 bytes).
  int xb = 128;
  const size_t need_per_xb = (size_t)NSEG * SEG_D * sizeof(float);
  while (xb > 1 && (size_t)xb * need_per_xb > ws_size) xb >>= 1;

  dim3 grid1(xb, NSEG);
  seg_partial_kernel<<<grid1, 256, 0, stream>>>(x, lengths, partial);
  seg_finish_kernel<<<NSEG, SEG_D, 0, stream>>>(partial, lengths, out, xb);
}